// Round 6
// baseline (64.090 us; speedup 1.0000x reference)
//
#include <hip/hip_runtime.h>

#define N_NODES 200000
#define NTILES  6250        // 32-node tiles, exact
#define NBLK    256         // 1 block/CU (128KB LDS)
#define TPB     512         // 8 waves, each independent after W-stage
#define NWAVES  2048        // NBLK * 8
#define NREP    64
#define LDS_BYTES 131072    // 64KB W1|W2 bf16 swizzled + 8 x 8KB per-wave h1

typedef __attribute__((ext_vector_type(8))) short short8;   // bf16x8 (4 VGPR)
typedef __attribute__((ext_vector_type(4))) float f32x4;
typedef __attribute__((ext_vector_type(4))) unsigned int u32x4;

__device__ __forceinline__ unsigned int f2bf(float f) {
  // round-to-nearest-even fp32 -> bf16 bits
  unsigned int u = __builtin_bit_cast(unsigned int, f);
  u += 0x7FFFu + ((u >> 16) & 1u);
  return u >> 16;
}
__device__ __forceinline__ unsigned int pk2(float a, float b) {
  return f2bf(a) | (f2bf(b) << 16);
}
__device__ __forceinline__ short8 pk8(f32x4 lo, f32x4 hi) {
  u32x4 u = { pk2(lo[0], lo[1]), pk2(lo[2], lo[3]),
              pk2(hi[0], hi[1]), pk2(hi[2], hi[3]) };
  return __builtin_bit_cast(short8, u);
}
__device__ __forceinline__ f32x4 mfma16(short8 a, short8 b, f32x4 c) {
  return __builtin_amdgcn_mfma_f32_16x16x32_bf16(a, b, c, 0, 0, 0);
}

__global__ __launch_bounds__(TPB, 1) void gcn_main(
    const float* __restrict__ x,  const float* __restrict__ W1,
    const float* __restrict__ b1, const float* __restrict__ W2,
    const float* __restrict__ b2, float* __restrict__ sums)
{
  extern __shared__ char lds[];
  char* const wlds = lds;                      // W1 @0, W2 @32768 (bf16 swz)
  const int tid  = threadIdx.x;
  const int lane = tid & 63;
  const int wid  = tid >> 6;
  char* const h1 = lds + 65536 + wid * 8192;   // PRIVATE per-wave slab
  const int r = lane & 15;                     // MFMA row/col-in-16
  const int g = lane >> 4;                     // k-group 0..3

  const int wgid = (int)blockIdx.x * 8 + wid;

  // ---- prologue: issue x loads for first tile (head start over W-stage) ----
  int t = wgid;                                // wgid < NTILES always
  f32x4 xf[8][2];                              // fp32 in flight, static idx
  {
    const float* bx = x + (size_t)t * 4096;
    #pragma unroll
    for (int nt = 0; nt < 2; ++nt)
      #pragma unroll
      for (int ks = 0; ks < 4; ++ks) {
        const float* p = bx + (nt * 16 + r) * 128 + ks * 32 + g * 8;
        xf[nt * 4 + ks][0] = *(const f32x4*)(p);
        xf[nt * 4 + ks][1] = *(const f32x4*)(p + 4);
      }
  }

  // ---- stage W1,W2 into LDS as swizzled bf16 A-tiles ----
  #pragma unroll
  for (int l = 0; l < 2; ++l) {
    const float* W = l ? W2 : W1;
    char* dst = wlds + l * 32768;
    #pragma unroll
    for (int i = 0; i < 4; ++i) {
      const int c = tid + i * 512;             // 16B-chunk id 0..2047
      const int f = c >> 4, s = c & 15;
      const f32x4* src = (const f32x4*)(W + f * 128 + s * 8);
      *(short8*)(dst + f * 256 + ((s ^ (f & 7)) << 4)) = pk8(src[0], src[1]);
    }
  }
  __syncthreads();   // the ONLY barrier; loop below is barrier-free

  const f32x4 zero4 = {0.f, 0.f, 0.f, 0.f};
  f32x4 sum8[8];
  #pragma unroll
  for (int ft = 0; ft < 8; ++ft) sum8[ft] = zero4;

  while (t < NTILES) {
    // pack current tile's B-frags -> frees xf for next-tile prefetch
    short8 xb[8];
    #pragma unroll
    for (int q = 0; q < 8; ++q) xb[q] = pk8(xf[q][0], xf[q][1]);

    const int tn = t + NWAVES;
    if (tn < NTILES) {                         // wave-uniform branch
      const float* bx = x + (size_t)tn * 4096;
      #pragma unroll
      for (int nt = 0; nt < 2; ++nt)
        #pragma unroll
        for (int ks = 0; ks < 4; ++ks) {
          const float* p = bx + (nt * 16 + r) * 128 + ks * 32 + g * 8;
          xf[nt * 4 + ks][0] = *(const f32x4*)(p);
          xf[nt * 4 + ks][1] = *(const f32x4*)(p + 4);
        }
    }

    // ---- layer 1: A = W1 (LDS), B = x frags; 2 passes of 4 f-tiles ----
    #pragma unroll
    for (int pass = 0; pass < 2; ++pass) {
      f32x4 acc[4][2];
      #pragma unroll
      for (int f4 = 0; f4 < 4; ++f4) { acc[f4][0] = zero4; acc[f4][1] = zero4; }
      #pragma unroll
      for (int ks = 0; ks < 4; ++ks) {
        #pragma unroll
        for (int f4 = 0; f4 < 4; ++f4) {
          const int ft = pass * 4 + f4;
          short8 af = *(const short8*)(wlds + (ft * 16 + r) * 256 +
                                       (((ks * 4 + g) ^ (r & 7)) << 4));
          acc[f4][0] = mfma16(af, xb[0 * 4 + ks], acc[f4][0]);
          acc[f4][1] = mfma16(af, xb[1 * 4 + ks], acc[f4][1]);
        }
      }
      // ---- epilogue 1: bias+relu, pack 4 features, b64 to private slab ----
      #pragma unroll
      for (int f4 = 0; f4 < 4; ++f4) {
        const int ft = pass * 4 + f4;
        const f32x4 bf = *(const f32x4*)(b1 + ft * 16 + g * 4);   // L1-hot
        const int s = ft * 2 + (g >> 1);
        const int half = (g & 1) * 8;
        #pragma unroll
        for (int nt = 0; nt < 2; ++nt) {
          const int n = nt * 16 + r;
          float v0 = fmaxf(acc[f4][nt][0] + bf[0], 0.f);
          float v1 = fmaxf(acc[f4][nt][1] + bf[1], 0.f);
          float v2 = fmaxf(acc[f4][nt][2] + bf[2], 0.f);
          float v3 = fmaxf(acc[f4][nt][3] + bf[3], 0.f);
          unsigned long long w =
              (unsigned long long)pk2(v0, v1) |
              ((unsigned long long)pk2(v2, v3) << 32);
          *(unsigned long long*)(h1 + n * 256 + ((s ^ (n & 7)) << 4) + half) = w;
        }
      }
    }

    // ---- layer 2: A = W2 (LDS), B = h1 slab; 2 passes of 4 f-tiles ----
    #pragma unroll
    for (int pass = 0; pass < 2; ++pass) {
      f32x4 acc[4][2];
      #pragma unroll
      for (int f4 = 0; f4 < 4; ++f4) { acc[f4][0] = zero4; acc[f4][1] = zero4; }
      #pragma unroll
      for (int ks = 0; ks < 4; ++ks) {
        const int n1 = 16 + r;
        short8 hb0 = *(const short8*)(h1 + r  * 256 +
                                      (((ks * 4 + g) ^ (r  & 7)) << 4));
        short8 hb1 = *(const short8*)(h1 + n1 * 256 +
                                      (((ks * 4 + g) ^ (n1 & 7)) << 4));
        #pragma unroll
        for (int f4 = 0; f4 < 4; ++f4) {
          const int ft = pass * 4 + f4;
          short8 af = *(const short8*)(wlds + 32768 + (ft * 16 + r) * 256 +
                                       (((ks * 4 + g) ^ (r & 7)) << 4));
          acc[f4][0] = mfma16(af, hb0, acc[f4][0]);
          acc[f4][1] = mfma16(af, hb1, acc[f4][1]);
        }
      }
      // ---- epilogue 2: bias+relu, accumulate column sums in registers ----
      #pragma unroll
      for (int f4 = 0; f4 < 4; ++f4) {
        const int ft = pass * 4 + f4;
        const f32x4 bf = *(const f32x4*)(b2 + ft * 16 + g * 4);
        #pragma unroll
        for (int nt = 0; nt < 2; ++nt)
          #pragma unroll
          for (int q = 0; q < 4; ++q)
            sum8[ft][q] += fmaxf(acc[f4][nt][q] + bf[q], 0.f);
      }
    }

    t = tn;
  }

  // ---- reduce over 16 node-lanes; g-lanes hold disjoint features ----
  #pragma unroll
  for (int ft = 0; ft < 8; ++ft)
    #pragma unroll
    for (int q = 0; q < 4; ++q) {
      float v = sum8[ft][q];
      v += __shfl_xor(v, 1, 64);
      v += __shfl_xor(v, 2, 64);
      v += __shfl_xor(v, 4, 64);
      v += __shfl_xor(v, 8, 64);
      sum8[ft][q] = v;
    }
  if (r == 0) {
    const int rep = wgid & (NREP - 1);
    #pragma unroll
    for (int ft = 0; ft < 8; ++ft)
      #pragma unroll
      for (int q = 0; q < 4; ++q)
        unsafeAtomicAdd(&sums[rep * 128 + ft * 16 + g * 4 + q], sum8[ft][q]);
  }
}

// mean -> W3 -> classifier -> log_softmax, fp32, trivial cost
__global__ void gcn_tail(const float* __restrict__ sums,
                         const float* __restrict__ W3, const float* __restrict__ b3,
                         const float* __restrict__ Wl, const float* __restrict__ bl,
                         float* __restrict__ out)
{
  __shared__ float h3[128];
  __shared__ float lg[16];
  int t = threadIdx.x;   // 128 threads
  float m = 0.f;
  for (int rp = 0; rp < NREP; ++rp) m += sums[rp * 128 + t];
  h3[t] = m * (1.0f / (float)N_NODES);
  __syncthreads();
  float accv = 0.f;
  for (int k = 0; k < 128; ++k) accv += h3[k] * W3[t * 128 + k];
  float h3o = b3[t] + accv;
  __syncthreads();
  h3[t] = h3o;
  __syncthreads();
  if (t < 10) {
    float a = bl[t];
    for (int j = 0; j < 128; ++j) a += h3[j] * Wl[t * 128 + j];
    lg[t] = a;
  }
  __syncthreads();
  if (t == 0) {
    float mx = lg[0];
    for (int c = 1; c < 10; ++c) mx = fmaxf(mx, lg[c]);
    float s = 0.f;
    for (int c = 0; c < 10; ++c) s += expf(lg[c] - mx);
    float lse = mx + logf(s);
    for (int c = 0; c < 10; ++c) out[c] = lg[c] - lse;
  }
}

extern "C" void kernel_launch(void* const* d_in, const int* in_sizes, int n_in,
                              void* d_out, int out_size, void* d_ws, size_t ws_size,
                              hipStream_t stream) {
  const float* x  = (const float*)d_in[0];
  // d_in[1] = edge_index (int64) — unused: ChebConv K=1 has no propagation
  const float* W1 = (const float*)d_in[2];
  const float* b1 = (const float*)d_in[3];
  const float* W2 = (const float*)d_in[4];
  const float* b2 = (const float*)d_in[5];
  const float* W3 = (const float*)d_in[6];
  const float* b3 = (const float*)d_in[7];
  const float* Wl = (const float*)d_in[8];
  const float* bl = (const float*)d_in[9];
  float* sums = (float*)d_ws;            // NREP x 128 floats
  float* out  = (float*)d_out;

  (void)hipFuncSetAttribute((const void*)gcn_main,
                            hipFuncAttributeMaxDynamicSharedMemorySize,
                            LDS_BYTES);
  (void)hipMemsetAsync(sums, 0, NREP * 128 * sizeof(float), stream);
  gcn_main<<<NBLK, TPB, LDS_BYTES, stream>>>(x, W1, b1, W2, b2, sums);
  gcn_tail<<<1, 128, 0, stream>>>(sums, W3, b3, Wl, bl, out);
}

// Round 7
// 57.441 us; speedup vs baseline: 1.1157x; 1.1157x over previous
//
#include <hip/hip_runtime.h>

#define N_NODES 200000
#define NTILES  6250        // 32-node tiles, exact
#define NBLK    256         // 1 block/CU (129KB LDS)
#define TPB     512         // 8 waves, independent after W-stage
#define NWAVES  2048        // NBLK * 8
#define NREP    64
#define LDS_BYTES 132096    // 64KB W + 1KB bias + 8 x 8KB per-wave h1

typedef __attribute__((ext_vector_type(8))) short short8;   // bf16x8 (4 VGPR)
typedef __attribute__((ext_vector_type(4))) float f32x4;
typedef __attribute__((ext_vector_type(4))) unsigned int u32x4;

__device__ __forceinline__ unsigned int pk2(float a, float b) {
  // single v_cvt_pk_bf16_f32 (T12 recipe): lo16 = bf16(a), hi16 = bf16(b)
  unsigned int d;
  asm("v_cvt_pk_bf16_f32 %0, %1, %2" : "=v"(d) : "v"(a), "v"(b));
  return d;
}
__device__ __forceinline__ short8 pk8(f32x4 lo, f32x4 hi) {
  u32x4 u = { pk2(lo[0], lo[1]), pk2(lo[2], lo[3]),
              pk2(hi[0], hi[1]), pk2(hi[2], hi[3]) };
  return __builtin_bit_cast(short8, u);
}
__device__ __forceinline__ f32x4 mfma16(short8 a, short8 b, f32x4 c) {
  return __builtin_amdgcn_mfma_f32_16x16x32_bf16(a, b, c, 0, 0, 0);
}

__global__ __launch_bounds__(TPB, 2) void gcn_main(
    const float* __restrict__ x,  const float* __restrict__ W1,
    const float* __restrict__ b1, const float* __restrict__ W2,
    const float* __restrict__ b2, float* __restrict__ sums)
{
  extern __shared__ char lds[];
  char*  const wlds = lds;                     // W1 @0, W2 @32768 (bf16 swz)
  float* const blds = (float*)(lds + 65536);   // b1[128] | b2[128]
  const int tid  = threadIdx.x;
  const int lane = tid & 63;
  const int wid  = tid >> 6;
  char* const h1 = lds + 66560 + wid * 8192;   // PRIVATE per-wave slab
  const int r = lane & 15;                     // MFMA row/col-in-16
  const int g = lane >> 4;                     // k-group 0..3

  // ---- stage W1,W2 (swizzled bf16 A-tiles) + biases into LDS ----
  if (tid < 128) { blds[tid] = b1[tid]; blds[128 + tid] = b2[tid]; }
  #pragma unroll
  for (int l = 0; l < 2; ++l) {
    const float* W = l ? W2 : W1;
    char* dst = wlds + l * 32768;
    #pragma unroll
    for (int i = 0; i < 4; ++i) {
      const int c = tid + i * 512;             // 16B-chunk id 0..2047
      const int f = c >> 4, s = c & 15;
      const f32x4* src = (const f32x4*)(W + f * 128 + s * 8);
      *(short8*)(dst + f * 256 + ((s ^ (f & 7)) << 4)) = pk8(src[0], src[1]);
    }
  }
  __syncthreads();   // the ONLY barrier; loop below is barrier-free

  // ---- contiguous per-wave tile range (bijective split of 6250) ----
  const int wgid = (int)blockIdx.x * 8 + wid;
  const int q = NTILES / NWAVES, rem = NTILES % NWAVES;   // 3, 106
  const int t0  = wgid * q + (wgid < rem ? wgid : rem);
  const int cnt = q + (wgid < rem ? 1 : 0);

  const f32x4 zero4 = {0.f, 0.f, 0.f, 0.f};
  f32x4 sum8[8];
  #pragma unroll
  for (int ft = 0; ft < 8; ++ft) sum8[ft] = zero4;

  for (int i = 0; i < cnt; ++i) {
    const int t = t0 + i;

    // ---- load + pack this tile's B-frags (transient fp32, no carry-over) ----
    const float* bx = x + (size_t)t * 4096;
    short8 xb[8];
    #pragma unroll
    for (int nt = 0; nt < 2; ++nt)
      #pragma unroll
      for (int ks = 0; ks < 4; ++ks) {
        const float* p = bx + (nt * 16 + r) * 128 + ks * 32 + g * 8;
        f32x4 lo = *(const f32x4*)(p);
        f32x4 hi = *(const f32x4*)(p + 4);
        xb[nt * 4 + ks] = pk8(lo, hi);
      }

    // ---- layer 1: A = W1 (LDS), B = x frags; 2 passes of 4 f-tiles ----
    #pragma unroll
    for (int pass = 0; pass < 2; ++pass) {
      f32x4 acc[4][2];
      #pragma unroll
      for (int f4 = 0; f4 < 4; ++f4) { acc[f4][0] = zero4; acc[f4][1] = zero4; }
      #pragma unroll
      for (int ks = 0; ks < 4; ++ks) {
        #pragma unroll
        for (int f4 = 0; f4 < 4; ++f4) {
          const int ft = pass * 4 + f4;
          short8 af = *(const short8*)(wlds + (ft * 16 + r) * 256 +
                                       (((ks * 4 + g) ^ (r & 7)) << 4));
          acc[f4][0] = mfma16(af, xb[0 * 4 + ks], acc[f4][0]);
          acc[f4][1] = mfma16(af, xb[1 * 4 + ks], acc[f4][1]);
        }
      }
      // epilogue 1: bias (LDS) + relu, pack, b64 to private slab
      #pragma unroll
      for (int f4 = 0; f4 < 4; ++f4) {
        const int ft = pass * 4 + f4;
        const f32x4 bf = *(const f32x4*)(blds + ft * 16 + g * 4);
        const int s = ft * 2 + (g >> 1);
        const int half = (g & 1) * 8;
        #pragma unroll
        for (int nt = 0; nt < 2; ++nt) {
          const int n = nt * 16 + r;
          float v0 = fmaxf(acc[f4][nt][0] + bf[0], 0.f);
          float v1 = fmaxf(acc[f4][nt][1] + bf[1], 0.f);
          float v2 = fmaxf(acc[f4][nt][2] + bf[2], 0.f);
          float v3 = fmaxf(acc[f4][nt][3] + bf[3], 0.f);
          unsigned long long w =
              (unsigned long long)pk2(v0, v1) |
              ((unsigned long long)pk2(v2, v3) << 32);
          *(unsigned long long*)(h1 + n * 256 + ((s ^ (n & 7)) << 4) + half) = w;
        }
      }
    }

    // ---- layer 2: A = W2 (LDS), B = h1 slab; 2 passes of 4 f-tiles ----
    #pragma unroll
    for (int pass = 0; pass < 2; ++pass) {
      f32x4 acc[4][2];
      #pragma unroll
      for (int f4 = 0; f4 < 4; ++f4) { acc[f4][0] = zero4; acc[f4][1] = zero4; }
      #pragma unroll
      for (int ks = 0; ks < 4; ++ks) {
        const int n1 = 16 + r;
        short8 hb0 = *(const short8*)(h1 + r  * 256 +
                                      (((ks * 4 + g) ^ (r  & 7)) << 4));
        short8 hb1 = *(const short8*)(h1 + n1 * 256 +
                                      (((ks * 4 + g) ^ (n1 & 7)) << 4));
        #pragma unroll
        for (int f4 = 0; f4 < 4; ++f4) {
          const int ft = pass * 4 + f4;
          short8 af = *(const short8*)(wlds + 32768 + (ft * 16 + r) * 256 +
                                       (((ks * 4 + g) ^ (r & 7)) << 4));
          acc[f4][0] = mfma16(af, hb0, acc[f4][0]);
          acc[f4][1] = mfma16(af, hb1, acc[f4][1]);
        }
      }
      // epilogue 2: bias (LDS) + relu, accumulate column sums in registers
      #pragma unroll
      for (int f4 = 0; f4 < 4; ++f4) {
        const int ft = pass * 4 + f4;
        const f32x4 bf = *(const f32x4*)(blds + 128 + ft * 16 + g * 4);
        #pragma unroll
        for (int nt = 0; nt < 2; ++nt)
          #pragma unroll
          for (int qq = 0; qq < 4; ++qq)
            sum8[ft][qq] += fmaxf(acc[f4][nt][qq] + bf[qq], 0.f);
      }
    }
  }

  // ---- reduce over 16 node-lanes; g-lanes hold disjoint features ----
  #pragma unroll
  for (int ft = 0; ft < 8; ++ft)
    #pragma unroll
    for (int qq = 0; qq < 4; ++qq) {
      float v = sum8[ft][qq];
      v += __shfl_xor(v, 1, 64);
      v += __shfl_xor(v, 2, 64);
      v += __shfl_xor(v, 4, 64);
      v += __shfl_xor(v, 8, 64);
      sum8[ft][qq] = v;
    }
  if (r == 0) {
    const int rep = wgid & (NREP - 1);
    #pragma unroll
    for (int ft = 0; ft < 8; ++ft)
      #pragma unroll
      for (int qq = 0; qq < 4; ++qq)
        unsafeAtomicAdd(&sums[rep * 128 + ft * 16 + g * 4 + qq], sum8[ft][qq]);
  }
}

// mean -> W3 -> classifier -> log_softmax, fp32, trivial cost
__global__ void gcn_tail(const float* __restrict__ sums,
                         const float* __restrict__ W3, const float* __restrict__ b3,
                         const float* __restrict__ Wl, const float* __restrict__ bl,
                         float* __restrict__ out)
{
  __shared__ float h3[128];
  __shared__ float lg[16];
  int t = threadIdx.x;   // 128 threads
  float m = 0.f;
  for (int rp = 0; rp < NREP; ++rp) m += sums[rp * 128 + t];
  h3[t] = m * (1.0f / (float)N_NODES);
  __syncthreads();
  float accv = 0.f;
  for (int k = 0; k < 128; ++k) accv += h3[k] * W3[t * 128 + k];
  float h3o = b3[t] + accv;
  __syncthreads();
  h3[t] = h3o;
  __syncthreads();
  if (t < 10) {
    float a = bl[t];
    for (int j = 0; j < 128; ++j) a += h3[j] * Wl[t * 128 + j];
    lg[t] = a;
  }
  __syncthreads();
  if (t == 0) {
    float mx = lg[0];
    for (int c = 1; c < 10; ++c) mx = fmaxf(mx, lg[c]);
    float s = 0.f;
    for (int c = 0; c < 10; ++c) s += expf(lg[c] - mx);
    float lse = mx + logf(s);
    for (int c = 0; c < 10; ++c) out[c] = lg[c] - lse;
  }
}

extern "C" void kernel_launch(void* const* d_in, const int* in_sizes, int n_in,
                              void* d_out, int out_size, void* d_ws, size_t ws_size,
                              hipStream_t stream) {
  const float* x  = (const float*)d_in[0];
  // d_in[1] = edge_index (int64) — unused: ChebConv K=1 has no propagation
  const float* W1 = (const float*)d_in[2];
  const float* b1 = (const float*)d_in[3];
  const float* W2 = (const float*)d_in[4];
  const float* b2 = (const float*)d_in[5];
  const float* W3 = (const float*)d_in[6];
  const float* b3 = (const float*)d_in[7];
  const float* Wl = (const float*)d_in[8];
  const float* bl = (const float*)d_in[9];
  float* sums = (float*)d_ws;            // NREP x 128 floats
  float* out  = (float*)d_out;

  (void)hipFuncSetAttribute((const void*)gcn_main,
                            hipFuncAttributeMaxDynamicSharedMemorySize,
                            LDS_BYTES);
  (void)hipMemsetAsync(sums, 0, NREP * 128 * sizeof(float), stream);
  gcn_main<<<NBLK, TPB, LDS_BYTES, stream>>>(x, W1, b1, W2, b2, sums);
  gcn_tail<<<1, 128, 0, stream>>>(sums, W3, b3, Wl, bl, out);
}